// Round 1
// 1333.530 us; speedup vs baseline: 1.1227x; 1.1227x over previous
//
#include <hip/hip_runtime.h>
#include <cstdint>
#include <cstddef>

typedef unsigned short u16;
typedef __bf16 bf16x8 __attribute__((ext_vector_type(8)));
typedef unsigned short u16x8 __attribute__((ext_vector_type(8)));
typedef unsigned short u16x4 __attribute__((ext_vector_type(4)));
typedef float f32x4 __attribute__((ext_vector_type(4)));

#define NB   16
#define TQ   2048
#define TV   2048
#define DDEC 1024   // decoder dim (query inner)
#define DENC 512    // encoder dim (value inner / Q' width)
#define CTXW (DENC + DDEC)  // 1536
#define CTXW2 (2*CTXW)      // 3072 : ctx row stride in u16

static __device__ __forceinline__ u16 f2bf(float f) {
    unsigned u = __builtin_bit_cast(unsigned, f);
    return (u16)((u + 0x7fffu + ((u >> 16) & 1u)) >> 16);  // RNE
}
static __device__ __forceinline__ float bf2f(u16 h) {
    return __builtin_bit_cast(float, ((unsigned)h) << 16);
}

// Stage one [128][32]-u16 tile (unpadded, 8 KB) global -> LDS via
// global_load_lds width=16. LDS base per chunk is wave-uniform; HW scatters
// lane i to base + i*16 (m97 structure).
static __device__ __forceinline__ void stage_tile(
    u16* __restrict__ lds_tile, const u16* __restrict__ gsrc,
    int ldb, int w, int lane)
{
    #pragma unroll
    for (int p = 0; p < 2; ++p) {
        const int ci  = p * 4 + w;               // chunk 0..7 (1024 B each)
        const int row = ci * 16 + (lane >> 2);
        const int col = (lane & 3) * 8;
        const u16* g = gsrc + (size_t)row * ldb + col;
        u16* l = lds_tile + ci * 512;            // wave-uniform chunk base
        __builtin_amdgcn_global_load_lds(
            (const __attribute__((address_space(1))) void*)g,
            (__attribute__((address_space(3))) void*)l, 16, 0, 0);
    }
}

// -------- elementwise hi/lo split: f32 -> bf16 hi + bf16 lo (same layout) ----
// Used for W [DENC,DDEC] and for Q [NB*TQ,DDEC] (grid scales with size).
__global__ __launch_bounds__(256)
void lk_prep_split(const float* __restrict__ X, u16* __restrict__ Xh, u16* __restrict__ Xl)
{
    const size_t i = ((size_t)blockIdx.x * 256 + threadIdx.x) * 4;
    const float4 v = *(const float4*)(X + i);
    const u16 h0=f2bf(v.x), h1=f2bf(v.y), h2=f2bf(v.z), h3=f2bf(v.w);
    u16x4 hv = {h0,h1,h2,h3};
    u16x4 lv = {f2bf(v.x-bf2f(h0)), f2bf(v.y-bf2f(h1)),
                f2bf(v.z-bf2f(h2)), f2bf(v.w-bf2f(h3))};
    *(u16x4*)(Xh + i) = hv;
    *(u16x4*)(Xl + i) = lv;
}

// -------- split V [NB,TV,DENC] -> Vh/Vl (same layout) + Vt hi [NB,DENC,TV] ---
__global__ __launch_bounds__(256)
void lk_prep_v(const float* __restrict__ V, u16* __restrict__ Vh,
               u16* __restrict__ Vl, u16* __restrict__ Vt)
{
    __shared__ float ts[32][36];
    const int t = threadIdx.x;
    const int r = t >> 3, c = (t & 7) * 4;
    const int e0 = blockIdx.x * 32, v0 = blockIdx.y * 32;
    const size_t bin  = (size_t)blockIdx.z * TV * DENC;
    const float4 v = *(const float4*)(V + bin + (size_t)(v0 + r) * DENC + e0 + c);
    *(float4*)&ts[r][c] = v;
    const u16 h0=f2bf(v.x), h1=f2bf(v.y), h2=f2bf(v.z), h3=f2bf(v.w);
    u16x4 hv = {h0,h1,h2,h3};
    u16x4 lv = {f2bf(v.x-bf2f(h0)), f2bf(v.y-bf2f(h1)),
                f2bf(v.z-bf2f(h2)), f2bf(v.w-bf2f(h3))};
    *(u16x4*)(Vh + bin + (size_t)(v0 + r) * DENC + e0 + c) = hv;
    *(u16x4*)(Vl + bin + (size_t)(v0 + r) * DENC + e0 + c) = lv;
    __syncthreads();
    u16x4 tv;
    #pragma unroll
    for (int x = 0; x < 4; ++x) tv[x] = f2bf(ts[c + x][r]);
    *(u16x4*)(Vt + (size_t)blockIdx.z * DENC * TV + (size_t)(e0 + r) * TV + v0 + c) = tv;
}

// ------- GEMM1: Q' = Q @ W^T (bf16x3). M=NB*TQ, N=DENC, K=DDEC. -------------
// All four operand tiles staged via global_load_lds (Q pre-split to Qh/Ql).
// Epilogue splits Q' -> hi/lo.
__global__ __launch_bounds__(256)
void lk_gemm_qw(const u16* __restrict__ Ah_g, const u16* __restrict__ Al_g,
                const u16* __restrict__ Bh_g, const u16* __restrict__ Bl_g,
                u16* __restrict__ Chi, u16* __restrict__ Clo)
{
    __shared__ u16 lAh[128*32], lAl[128*32], lBh[128*32], lBl[128*32];
    const int m0 = blockIdx.x * 128, n0 = blockIdx.y * 128;
    const int t = threadIdx.x;
    const int w = t >> 6, lane = t & 63, l15 = lane & 15, quad = lane >> 4;

    const u16* Ab_h = Ah_g + (size_t)m0 * DDEC;
    const u16* Ab_l = Al_g + (size_t)m0 * DDEC;
    const u16* Bb_h = Bh_g + (size_t)n0 * DDEC;
    const u16* Bb_l = Bl_g + (size_t)n0 * DDEC;

    f32x4 acc[2][8];
    #pragma unroll
    for (int i = 0; i < 2; ++i)
        #pragma unroll
        for (int j = 0; j < 8; ++j) acc[i][j] = (f32x4){0.f,0.f,0.f,0.f};

    for (int k0 = 0; k0 < DDEC; k0 += 32) {
        stage_tile(lAh, Ab_h + k0, DDEC, w, lane);
        stage_tile(lAl, Ab_l + k0, DDEC, w, lane);
        stage_tile(lBh, Bb_h + k0, DDEC, w, lane);
        stage_tile(lBl, Bb_l + k0, DDEC, w, lane);
        __syncthreads();
        bf16x8 ah[2], al[2];
        #pragma unroll
        for (int tm = 0; tm < 2; ++tm) {
            const int row = w*32 + tm*16 + l15;
            ah[tm] = __builtin_bit_cast(bf16x8, *(const u16x8*)&lAh[row*32 + quad*8]);
            al[tm] = __builtin_bit_cast(bf16x8, *(const u16x8*)&lAl[row*32 + quad*8]);
        }
        #pragma unroll
        for (int tn = 0; tn < 8; ++tn) {
            const int col = tn*16 + l15;
            const bf16x8 bh = __builtin_bit_cast(bf16x8, *(const u16x8*)&lBh[col*32 + quad*8]);
            const bf16x8 bl = __builtin_bit_cast(bf16x8, *(const u16x8*)&lBl[col*32 + quad*8]);
            #pragma unroll
            for (int tm = 0; tm < 2; ++tm) {
                acc[tm][tn] = __builtin_amdgcn_mfma_f32_16x16x32_bf16(ah[tm], bh, acc[tm][tn], 0,0,0);
                acc[tm][tn] = __builtin_amdgcn_mfma_f32_16x16x32_bf16(ah[tm], bl, acc[tm][tn], 0,0,0);
                acc[tm][tn] = __builtin_amdgcn_mfma_f32_16x16x32_bf16(al[tm], bh, acc[tm][tn], 0,0,0);
            }
        }
        __syncthreads();
    }
    #pragma unroll
    for (int tn = 0; tn < 8; ++tn) {
        const int col = n0 + tn*16 + l15;
        #pragma unroll
        for (int tm = 0; tm < 2; ++tm)
            #pragma unroll
            for (int r = 0; r < 4; ++r) {
                const int row = m0 + w*32 + tm*16 + quad*4 + r;
                const float c = acc[tm][tn][r];
                const u16 h = f2bf(c);
                Chi[(size_t)row*DENC + col] = h;
                Clo[(size_t)row*DENC + col] = f2bf(c - bf2f(h));
            }
    }
}

// ------- GEMM2: scores[b,q,v] = Q'[b] @ V[b]^T (bf16x3), K=DENC=512 ----------
// All four operand tiles staged via global_load_lds (no VALU split in loop).
__global__ __launch_bounds__(256)
void lk_gemm_scores(const u16* __restrict__ Ah_g, const u16* __restrict__ Al_g,
                    const u16* __restrict__ Bh_g, const u16* __restrict__ Bl_g,
                    float* __restrict__ Sc)
{
    __shared__ u16 lAh[128*32], lAl[128*32], lBh[128*32], lBl[128*32];
    const int b = blockIdx.z;
    const int m0 = blockIdx.x * 128, n0 = blockIdx.y * 128;
    const int t = threadIdx.x;
    const int w = t >> 6, lane = t & 63, l15 = lane & 15, quad = lane >> 4;

    const u16* Ab_h = Ah_g + (size_t)b * TQ * DENC + (size_t)m0 * DENC;
    const u16* Ab_l = Al_g + (size_t)b * TQ * DENC + (size_t)m0 * DENC;
    const u16* Bb_h = Bh_g + (size_t)b * TV * DENC + (size_t)n0 * DENC;
    const u16* Bb_l = Bl_g + (size_t)b * TV * DENC + (size_t)n0 * DENC;

    f32x4 acc[2][8];
    #pragma unroll
    for (int i = 0; i < 2; ++i)
        #pragma unroll
        for (int j = 0; j < 8; ++j) acc[i][j] = (f32x4){0.f,0.f,0.f,0.f};

    for (int k0 = 0; k0 < DENC; k0 += 32) {
        stage_tile(lAh, Ab_h + k0, DENC, w, lane);
        stage_tile(lAl, Ab_l + k0, DENC, w, lane);
        stage_tile(lBh, Bb_h + k0, DENC, w, lane);
        stage_tile(lBl, Bb_l + k0, DENC, w, lane);
        __syncthreads();
        bf16x8 ah[2], al[2];
        #pragma unroll
        for (int tm = 0; tm < 2; ++tm) {
            const int row = w*32 + tm*16 + l15;
            ah[tm] = __builtin_bit_cast(bf16x8, *(const u16x8*)&lAh[row*32 + quad*8]);
            al[tm] = __builtin_bit_cast(bf16x8, *(const u16x8*)&lAl[row*32 + quad*8]);
        }
        #pragma unroll
        for (int tn = 0; tn < 8; ++tn) {
            const int col = tn*16 + l15;
            const bf16x8 bh = __builtin_bit_cast(bf16x8, *(const u16x8*)&lBh[col*32 + quad*8]);
            const bf16x8 bl = __builtin_bit_cast(bf16x8, *(const u16x8*)&lBl[col*32 + quad*8]);
            #pragma unroll
            for (int tm = 0; tm < 2; ++tm) {
                acc[tm][tn] = __builtin_amdgcn_mfma_f32_16x16x32_bf16(ah[tm], bh, acc[tm][tn], 0,0,0);
                acc[tm][tn] = __builtin_amdgcn_mfma_f32_16x16x32_bf16(ah[tm], bl, acc[tm][tn], 0,0,0);
                acc[tm][tn] = __builtin_amdgcn_mfma_f32_16x16x32_bf16(al[tm], bh, acc[tm][tn], 0,0,0);
            }
        }
        __syncthreads();
    }
    float* Sb = Sc + (size_t)b * TQ * TV;
    #pragma unroll
    for (int tm = 0; tm < 2; ++tm)
        #pragma unroll
        for (int tn = 0; tn < 8; ++tn) {
            const int col = n0 + tn*16 + l15;
            #pragma unroll
            for (int r = 0; r < 4; ++r) {
                const int row = m0 + w*32 + tm*16 + quad*4 + r;
                Sb[(size_t)row*TV + col] = acc[tm][tn][r];
            }
        }
}

// ---------------- softmax rows in place: [NB*TQ, TV] -------------------------
// Also emits bf16 P into the (dead-until-copy_q) q-part of the ctx row:
// u16 cols [1024, 3072) of ctx row r. gemm_ctx stages A from there and writes
// only u16 cols [0,1024) -> no overlap, race-free.
__global__ __launch_bounds__(256)
void lk_softmax(float* __restrict__ S, u16* __restrict__ Pbf)
{
    const size_t row = blockIdx.x;
    float* p = S + row * TV;
    u16* pb = Pbf + row * CTXW2 + 2*DENC;
    const int t = threadIdx.x;
    const float4 v0 = *(const float4*)(p + 4*t);
    const float4 v1 = *(const float4*)(p + 1024 + 4*t);
    float mx = fmaxf(fmaxf(fmaxf(v0.x, v0.y), fmaxf(v0.z, v0.w)),
                     fmaxf(fmaxf(v1.x, v1.y), fmaxf(v1.z, v1.w)));
    #pragma unroll
    for (int off = 32; off > 0; off >>= 1) mx = fmaxf(mx, __shfl_xor(mx, off, 64));
    __shared__ float sred[4];
    const int w = t >> 6;
    if ((t & 63) == 0) sred[w] = mx;
    __syncthreads();
    mx = fmaxf(fmaxf(sred[0], sred[1]), fmaxf(sred[2], sred[3]));
    __syncthreads();
    float e[8];
    e[0]=__expf(v0.x-mx); e[1]=__expf(v0.y-mx); e[2]=__expf(v0.z-mx); e[3]=__expf(v0.w-mx);
    e[4]=__expf(v1.x-mx); e[5]=__expf(v1.y-mx); e[6]=__expf(v1.z-mx); e[7]=__expf(v1.w-mx);
    float s = ((e[0]+e[1])+(e[2]+e[3])) + ((e[4]+e[5])+(e[6]+e[7]));
    #pragma unroll
    for (int off = 32; off > 0; off >>= 1) s += __shfl_xor(s, off, 64);
    if ((t & 63) == 0) sred[w] = s;
    __syncthreads();
    s = (sred[0]+sred[1]) + (sred[2]+sred[3]);
    const float inv = 1.0f / s;
    float4 o0 = {e[0]*inv, e[1]*inv, e[2]*inv, e[3]*inv};
    float4 o1 = {e[4]*inv, e[5]*inv, e[6]*inv, e[7]*inv};
    *(float4*)(p + 4*t) = o0;
    *(float4*)(p + 1024 + 4*t) = o1;
    u16x4 b0 = {f2bf(o0.x), f2bf(o0.y), f2bf(o0.z), f2bf(o0.w)};
    u16x4 b1 = {f2bf(o1.x), f2bf(o1.y), f2bf(o1.z), f2bf(o1.w)};
    *(u16x4*)(pb + 4*t) = b0;
    *(u16x4*)(pb + 1024 + 4*t) = b1;
}

// ------- GEMM3: context = align @ value  (single bf16; NT via Vt) ------------
// A = bf16 P interleaved in ctx rows (u16 cols [1024,3072), ld=3072), staged
// via global_load_lds. Writes only f32 cols [0,512) of the same rows.
__global__ __launch_bounds__(256)
void lk_gemm_ctx(const u16* __restrict__ Vt, float* C)
{
    __shared__ u16 lA[128*32], lB[128*32];
    const int b = blockIdx.z;
    const int m0 = blockIdx.x * 128, n0 = blockIdx.y * 128;
    const int t = threadIdx.x;
    const int w = t >> 6, lane = t & 63, l15 = lane & 15, quad = lane >> 4;

    const u16* Pb = (const u16*)C + ((size_t)b * TQ + m0) * CTXW2 + 2*DENC;
    const u16* Bb = Vt + (size_t)b * DENC * TV + (size_t)n0 * TV;

    f32x4 acc[2][8];
    #pragma unroll
    for (int i = 0; i < 2; ++i)
        #pragma unroll
        for (int j = 0; j < 8; ++j) acc[i][j] = (f32x4){0.f,0.f,0.f,0.f};

    for (int k0 = 0; k0 < TV; k0 += 32) {
        stage_tile(lA, Pb + k0, CTXW2, w, lane);
        stage_tile(lB, Bb + k0, TV, w, lane);
        __syncthreads();
        bf16x8 af[2];
        #pragma unroll
        for (int tm = 0; tm < 2; ++tm) {
            const int row = w*32 + tm*16 + l15;
            af[tm] = __builtin_bit_cast(bf16x8, *(const u16x8*)&lA[row*32 + quad*8]);
        }
        #pragma unroll
        for (int tn = 0; tn < 8; ++tn) {
            const int col = tn*16 + l15;
            const bf16x8 bf = __builtin_bit_cast(bf16x8, *(const u16x8*)&lB[col*32 + quad*8]);
            #pragma unroll
            for (int tm = 0; tm < 2; ++tm)
                acc[tm][tn] = __builtin_amdgcn_mfma_f32_16x16x32_bf16(af[tm], bf, acc[tm][tn], 0,0,0);
        }
        __syncthreads();
    }
    float* Cb = C + (size_t)b * TQ * CTXW;
    #pragma unroll
    for (int tm = 0; tm < 2; ++tm)
        #pragma unroll
        for (int tn = 0; tn < 8; ++tn) {
            const int col = n0 + tn*16 + l15;
            #pragma unroll
            for (int r = 0; r < 4; ++r) {
                const int row = m0 + w*32 + tm*16 + quad*4 + r;
                Cb[(size_t)row*CTXW + col] = acc[tm][tn][r];
            }
        }
}

// ---------------- copy query into ctx cols [DENC, DENC+DDEC) -----------------
__global__ __launch_bounds__(256)
void lk_copy_q(const float* __restrict__ Q, float* __restrict__ C)
{
    const size_t idx = (size_t)blockIdx.x * 256 + threadIdx.x;   // float4 index
    const int d4 = (int)(idx & 255);       // DDEC/4 = 256
    const size_t row = idx >> 8;           // b*TQ + q
    const float4 v = *(const float4*)(Q + (row << 10) + 4*d4);
    *(float4*)(C + row * CTXW + DENC + 4*d4) = v;
}

// ---------------- in-place square transpose per batch: [TQ,TV] --------------
__global__ __launch_bounds__(256)
void lk_transpose(float* __restrict__ A)
{
    const int i = blockIdx.x, j = blockIdx.y;
    if (j < i) return;
    float* Ab = A + (size_t)blockIdx.z * TQ * TV;
    __shared__ float ta[32][36], tb[32][36];
    const int t = threadIdx.x;
    const int r = t >> 3, c = (t & 7) * 4;
    float* pij = Ab + (size_t)(i*32) * TV + j*32;
    float* pji = Ab + (size_t)(j*32) * TV + i*32;
    const float4 va = *(const float4*)(pij + (size_t)r * TV + c);
    *(float4*)&ta[r][c] = va;
    if (i != j) {
        const float4 vb = *(const float4*)(pji + (size_t)r * TV + c);
        *(float4*)&tb[r][c] = vb;
    }
    __syncthreads();
    float4 oa = { ta[c+0][r], ta[c+1][r], ta[c+2][r], ta[c+3][r] };
    *(float4*)(pji + (size_t)r * TV + c) = oa;
    if (i != j) {
        float4 ob = { tb[c+0][r], tb[c+1][r], tb[c+2][r], tb[c+3][r] };
        *(float4*)(pij + (size_t)r * TV + c) = ob;
    }
}

extern "C" void kernel_launch(void* const* d_in, const int* in_sizes, int n_in,
                              void* d_out, int out_size, void* d_ws, size_t ws_size,
                              hipStream_t stream)
{
    (void)in_sizes; (void)n_in; (void)out_size; (void)ws_size;
    const float* Q = (const float*)d_in[0];
    const float* V = (const float*)d_in[1];
    const float* W = (const float*)d_in[2];
    // d_in[3] = bias: softmax-invariant (adds Q·b, constant over v) -> dropped.
    float* out = (float*)d_out;

    float* ctx   = out;                                   // [NB, TQ, CTXW]
    float* align = out + (size_t)NB * TQ * CTXW;          // [NB, TQ, TV]

    // Scores operands staged in the (dead-until-gemm_ctx) ctx region:
    // Q'h/Q'l [NB,TQ,DENC] + Vh/Vl [NB,TV,DENC] = 134 MB < 201 MB.
    u16* q2h = (u16*)ctx;
    u16* q2l = q2h + (size_t)NB * TQ * DENC;
    u16* vsh = q2l + (size_t)NB * TQ * DENC;
    u16* vsl = vsh + (size_t)NB * TV * DENC;

    // Qh/Ql bf16 [NB*TQ, DDEC] staged in the (dead-until-scores) align region:
    // 2 x 67 MB = 134 MB < 268 MB.
    u16* qh = (u16*)align;
    u16* ql = qh + (size_t)NB * TQ * DDEC;

    // ws: Wh/Wl (2.1 MB) + Vt bf16 [NB,DENC,TV] (33.6 MB)
    u16* wh = (u16*)d_ws;
    u16* wl = wh + (size_t)DENC * DDEC;
    u16* vt = wl + (size_t)DENC * DDEC;

    lk_prep_split<<<DENC*DDEC/1024, 256, 0, stream>>>(W, wh, wl);
    lk_prep_split<<<(size_t)NB*TQ*DDEC/1024, 256, 0, stream>>>(Q, qh, ql);
    lk_prep_v<<<dim3(DENC/32, TV/32, NB), 256, 0, stream>>>(V, vsh, vsl, vt);
    lk_gemm_qw<<<dim3(NB*TQ/128, DENC/128), 256, 0, stream>>>(qh, ql, wh, wl, q2h, q2l);
    lk_gemm_scores<<<dim3(TQ/128, TV/128, NB), 256, 0, stream>>>(q2h, q2l, vsh, vsl, align);
    lk_softmax<<<NB*TQ, 256, 0, stream>>>(align, (u16*)ctx);
    lk_gemm_ctx<<<dim3(TQ/128, DENC/128, NB), 256, 0, stream>>>(vt, ctx);
    lk_copy_q<<<NB*TQ*DDEC/1024, 256, 0, stream>>>(Q, ctx);
    lk_transpose<<<dim3(TV/32, TV/32, NB), 256, 0, stream>>>(align);
}

// Round 2
// 1294.312 us; speedup vs baseline: 1.1567x; 1.0303x over previous
//
#include <hip/hip_runtime.h>
#include <cstdint>
#include <cstddef>

typedef unsigned short u16;
typedef __bf16 bf16x8 __attribute__((ext_vector_type(8)));
typedef unsigned short u16x8 __attribute__((ext_vector_type(8)));
typedef unsigned short u16x4 __attribute__((ext_vector_type(4)));
typedef float f32x4 __attribute__((ext_vector_type(4)));

#define NB   16
#define TQ   2048
#define TV   2048
#define DDEC 1024   // decoder dim (query inner)
#define DENC 512    // encoder dim (value inner / Q' width)
#define CTXW (DENC + DDEC)  // 1536
#define CTXW2 (2*CTXW)      // 3072 : ctx row stride in u16

static __device__ __forceinline__ u16 f2bf(float f) {
    unsigned u = __builtin_bit_cast(unsigned, f);
    return (u16)((u + 0x7fffu + ((u >> 16) & 1u)) >> 16);  // RNE
}
static __device__ __forceinline__ float bf2f(u16 h) {
    return __builtin_bit_cast(float, ((unsigned)h) << 16);
}

// Stage one [128][32]-u16 tile (unpadded, 8 KB) global -> LDS via
// global_load_lds width=16. LDS base per chunk is wave-uniform; HW scatters
// lane i to base + i*16 (m97 structure).
static __device__ __forceinline__ void stage_tile(
    u16* __restrict__ lds_tile, const u16* __restrict__ gsrc,
    int ldb, int w, int lane)
{
    #pragma unroll
    for (int p = 0; p < 2; ++p) {
        const int ci  = p * 4 + w;               // chunk 0..7 (1024 B each)
        const int row = ci * 16 + (lane >> 2);
        const int col = (lane & 3) * 8;
        const u16* g = gsrc + (size_t)row * ldb + col;
        u16* l = lds_tile + ci * 512;            // wave-uniform chunk base
        __builtin_amdgcn_global_load_lds(
            (const __attribute__((address_space(1))) void*)g,
            (__attribute__((address_space(3))) void*)l, 16, 0, 0);
    }
}

// -------- elementwise hi/lo split: f32 -> bf16 hi + bf16 lo (same layout) ----
// Used for W [DENC,DDEC], Q [NB*TQ,DDEC], V [NB,TV,DENC].
__global__ __launch_bounds__(256)
void lk_prep_split(const float* __restrict__ X, u16* __restrict__ Xh, u16* __restrict__ Xl)
{
    const size_t i = ((size_t)blockIdx.x * 256 + threadIdx.x) * 4;
    const float4 v = *(const float4*)(X + i);
    const u16 h0=f2bf(v.x), h1=f2bf(v.y), h2=f2bf(v.z), h3=f2bf(v.w);
    u16x4 hv = {h0,h1,h2,h3};
    u16x4 lv = {f2bf(v.x-bf2f(h0)), f2bf(v.y-bf2f(h1)),
                f2bf(v.z-bf2f(h2)), f2bf(v.w-bf2f(h3))};
    *(u16x4*)(Xh + i) = hv;
    *(u16x4*)(Xl + i) = lv;
}

// -------- Vt bf16 [NB,DENC,TV] from pristine f32 V [NB,TV,DENC] --------------
// Runs AFTER norm_t (its ws region aliases the dead softmax-stats buffer).
__global__ __launch_bounds__(256)
void lk_prep_vt(const float* __restrict__ V, u16* __restrict__ Vt)
{
    __shared__ float ts[32][36];
    const int t = threadIdx.x;
    const int r = t >> 3, c = (t & 7) * 4;
    const int e0 = blockIdx.x * 32, v0 = blockIdx.y * 32;
    const float* Vb = V + (size_t)blockIdx.z * TV * DENC;
    const float4 v = *(const float4*)(Vb + (size_t)(v0 + r) * DENC + e0 + c);
    *(float4*)&ts[r][c] = v;
    __syncthreads();
    u16x4 tv = { f2bf(ts[c+0][r]), f2bf(ts[c+1][r]),
                 f2bf(ts[c+2][r]), f2bf(ts[c+3][r]) };
    *(u16x4*)(Vt + (size_t)blockIdx.z * DENC * TV + (size_t)(e0 + r) * TV + v0 + c) = tv;
}

// ------- GEMM1: Q' = Q @ W^T (bf16x3). M=NB*TQ, N=DENC, K=DDEC. -------------
__global__ __launch_bounds__(256)
void lk_gemm_qw(const u16* __restrict__ Ah_g, const u16* __restrict__ Al_g,
                const u16* __restrict__ Bh_g, const u16* __restrict__ Bl_g,
                u16* __restrict__ Chi, u16* __restrict__ Clo)
{
    __shared__ u16 lAh[128*32], lAl[128*32], lBh[128*32], lBl[128*32];
    const int m0 = blockIdx.x * 128, n0 = blockIdx.y * 128;
    const int t = threadIdx.x;
    const int w = t >> 6, lane = t & 63, l15 = lane & 15, quad = lane >> 4;

    const u16* Ab_h = Ah_g + (size_t)m0 * DDEC;
    const u16* Ab_l = Al_g + (size_t)m0 * DDEC;
    const u16* Bb_h = Bh_g + (size_t)n0 * DDEC;
    const u16* Bb_l = Bl_g + (size_t)n0 * DDEC;

    f32x4 acc[2][8];
    #pragma unroll
    for (int i = 0; i < 2; ++i)
        #pragma unroll
        for (int j = 0; j < 8; ++j) acc[i][j] = (f32x4){0.f,0.f,0.f,0.f};

    for (int k0 = 0; k0 < DDEC; k0 += 32) {
        stage_tile(lAh, Ab_h + k0, DDEC, w, lane);
        stage_tile(lAl, Ab_l + k0, DDEC, w, lane);
        stage_tile(lBh, Bb_h + k0, DDEC, w, lane);
        stage_tile(lBl, Bb_l + k0, DDEC, w, lane);
        __syncthreads();
        bf16x8 ah[2], al[2];
        #pragma unroll
        for (int tm = 0; tm < 2; ++tm) {
            const int row = w*32 + tm*16 + l15;
            ah[tm] = __builtin_bit_cast(bf16x8, *(const u16x8*)&lAh[row*32 + quad*8]);
            al[tm] = __builtin_bit_cast(bf16x8, *(const u16x8*)&lAl[row*32 + quad*8]);
        }
        #pragma unroll
        for (int tn = 0; tn < 8; ++tn) {
            const int col = tn*16 + l15;
            const bf16x8 bh = __builtin_bit_cast(bf16x8, *(const u16x8*)&lBh[col*32 + quad*8]);
            const bf16x8 bl = __builtin_bit_cast(bf16x8, *(const u16x8*)&lBl[col*32 + quad*8]);
            #pragma unroll
            for (int tm = 0; tm < 2; ++tm) {
                acc[tm][tn] = __builtin_amdgcn_mfma_f32_16x16x32_bf16(ah[tm], bh, acc[tm][tn], 0,0,0);
                acc[tm][tn] = __builtin_amdgcn_mfma_f32_16x16x32_bf16(ah[tm], bl, acc[tm][tn], 0,0,0);
                acc[tm][tn] = __builtin_amdgcn_mfma_f32_16x16x32_bf16(al[tm], bh, acc[tm][tn], 0,0,0);
            }
        }
        __syncthreads();
    }
    #pragma unroll
    for (int tn = 0; tn < 8; ++tn) {
        const int col = n0 + tn*16 + l15;
        #pragma unroll
        for (int tm = 0; tm < 2; ++tm)
            #pragma unroll
            for (int r = 0; r < 4; ++r) {
                const int row = m0 + w*32 + tm*16 + quad*4 + r;
                const float c = acc[tm][tn][r];
                const u16 h = f2bf(c);
                Chi[(size_t)row*DENC + col] = h;
                Clo[(size_t)row*DENC + col] = f2bf(c - bf2f(h));
            }
    }
}

// ------- GEMM2: scores[b,q,v] = Q'[b] @ V[b]^T (bf16x3), K=DENC=512 ----------
// Epilogue also emits per-(row, col-block) partial softmax stats (max, sumexp).
__global__ __launch_bounds__(256)
void lk_gemm_scores(const u16* __restrict__ Ah_g, const u16* __restrict__ Al_g,
                    const u16* __restrict__ Bh_g, const u16* __restrict__ Bl_g,
                    float* __restrict__ Sc, float2* __restrict__ sst)
{
    __shared__ u16 lAh[128*32], lAl[128*32], lBh[128*32], lBl[128*32];
    const int b = blockIdx.z;
    const int m0 = blockIdx.x * 128, n0 = blockIdx.y * 128;
    const int t = threadIdx.x;
    const int w = t >> 6, lane = t & 63, l15 = lane & 15, quad = lane >> 4;

    const u16* Ab_h = Ah_g + (size_t)b * TQ * DENC + (size_t)m0 * DENC;
    const u16* Ab_l = Al_g + (size_t)b * TQ * DENC + (size_t)m0 * DENC;
    const u16* Bb_h = Bh_g + (size_t)b * TV * DENC + (size_t)n0 * DENC;
    const u16* Bb_l = Bl_g + (size_t)b * TV * DENC + (size_t)n0 * DENC;

    f32x4 acc[2][8];
    #pragma unroll
    for (int i = 0; i < 2; ++i)
        #pragma unroll
        for (int j = 0; j < 8; ++j) acc[i][j] = (f32x4){0.f,0.f,0.f,0.f};

    for (int k0 = 0; k0 < DENC; k0 += 32) {
        stage_tile(lAh, Ab_h + k0, DENC, w, lane);
        stage_tile(lAl, Ab_l + k0, DENC, w, lane);
        stage_tile(lBh, Bb_h + k0, DENC, w, lane);
        stage_tile(lBl, Bb_l + k0, DENC, w, lane);
        __syncthreads();
        bf16x8 ah[2], al[2];
        #pragma unroll
        for (int tm = 0; tm < 2; ++tm) {
            const int row = w*32 + tm*16 + l15;
            ah[tm] = __builtin_bit_cast(bf16x8, *(const u16x8*)&lAh[row*32 + quad*8]);
            al[tm] = __builtin_bit_cast(bf16x8, *(const u16x8*)&lAl[row*32 + quad*8]);
        }
        #pragma unroll
        for (int tn = 0; tn < 8; ++tn) {
            const int col = tn*16 + l15;
            const bf16x8 bh = __builtin_bit_cast(bf16x8, *(const u16x8*)&lBh[col*32 + quad*8]);
            const bf16x8 bl = __builtin_bit_cast(bf16x8, *(const u16x8*)&lBl[col*32 + quad*8]);
            #pragma unroll
            for (int tm = 0; tm < 2; ++tm) {
                acc[tm][tn] = __builtin_amdgcn_mfma_f32_16x16x32_bf16(ah[tm], bh, acc[tm][tn], 0,0,0);
                acc[tm][tn] = __builtin_amdgcn_mfma_f32_16x16x32_bf16(ah[tm], bl, acc[tm][tn], 0,0,0);
                acc[tm][tn] = __builtin_amdgcn_mfma_f32_16x16x32_bf16(al[tm], bh, acc[tm][tn], 0,0,0);
            }
        }
        __syncthreads();
    }
    float* Sb = Sc + (size_t)b * TQ * TV;
    #pragma unroll
    for (int tm = 0; tm < 2; ++tm)
        #pragma unroll
        for (int tn = 0; tn < 8; ++tn) {
            const int col = n0 + tn*16 + l15;
            #pragma unroll
            for (int r = 0; r < 4; ++r) {
                const int row = m0 + w*32 + tm*16 + quad*4 + r;
                Sb[(size_t)row*TV + col] = acc[tm][tn][r];
            }
        }
    // partial softmax stats for this block's 128 columns.
    // Row (w,tm,quad,r) is held by the 16 lanes quad*16..quad*16+15 (l15=0..15),
    // each owning cols {tn*16+l15}. In-thread reduce over tn, then 16-lane xor.
    const int by = blockIdx.y;
    #pragma unroll
    for (int tm = 0; tm < 2; ++tm)
        #pragma unroll
        for (int r = 0; r < 4; ++r) {
            float m = acc[tm][0][r];
            #pragma unroll
            for (int tn = 1; tn < 8; ++tn) m = fmaxf(m, acc[tm][tn][r]);
            #pragma unroll
            for (int off = 1; off < 16; off <<= 1) m = fmaxf(m, __shfl_xor(m, off, 64));
            float s = 0.f;
            #pragma unroll
            for (int tn = 0; tn < 8; ++tn) s += __expf(acc[tm][tn][r] - m);
            #pragma unroll
            for (int off = 1; off < 16; off <<= 1) s += __shfl_xor(s, off, 64);
            if (l15 == 0) {
                const int row = m0 + w*32 + tm*16 + quad*4 + r;
                sst[((size_t)(b*16 + by))*TQ + row] = (float2){m, s};
            }
        }
}

// ------- combine partial stats -> per-row (max, 1/sum) in the y=0 slot -------
__global__ __launch_bounds__(256)
void lk_combine(float2* __restrict__ sst)
{
    const int rg = blockIdx.x * 256 + threadIdx.x;   // [0, NB*TQ)
    const int b = rg >> 11, q = rg & (TQ - 1);
    float2* base = sst + (size_t)b * 16 * TQ;
    float2 v[16];
    float mx = -3.0e38f;
    #pragma unroll
    for (int y = 0; y < 16; ++y) {
        v[y] = base[(size_t)y * TQ + q];
        mx = fmaxf(mx, v[y].x);
    }
    float s = 0.f;
    #pragma unroll
    for (int y = 0; y < 16; ++y) s += v[y].y * __expf(v[y].x - mx);
    base[q] = (float2){mx, 1.0f / s};   // own slot only -> race-free
}

// ------- fused normalize + in-place transpose + bf16-P emit ------------------
// Reads raw S [q,v], applies exp(s-mx)*inv, writes alignment^T f32 in place
// (pairwise 32x32 tile swap) and bf16 P into ctx rows (u16 cols [1024,3072)).
__global__ __launch_bounds__(256)
void lk_norm_t(float* __restrict__ A, float* __restrict__ C,
               const float2* __restrict__ sstF)
{
    const int i = blockIdx.x, j = blockIdx.y;
    if (j < i) return;
    const int b = blockIdx.z;
    float* Ab = A + (size_t)b * TQ * TV;
    u16* Pb = (u16*)C + (size_t)b * TQ * CTXW2 + 2*DENC;
    const float2* st = sstF + (size_t)b * 16 * TQ;   // finals in y=0 slots
    __shared__ float ta[32][36], tb[32][36];
    const int t = threadIdx.x;
    const int r = t >> 3, c = (t & 7) * 4;
    float* pij = Ab + (size_t)(i*32) * TV + j*32;
    float* pji = Ab + (size_t)(j*32) * TV + i*32;
    {
        const float2 s2 = st[i*32 + r];
        const float4 va = *(const float4*)(pij + (size_t)r * TV + c);
        float4 e = { __expf(va.x - s2.x) * s2.y, __expf(va.y - s2.x) * s2.y,
                     __expf(va.z - s2.x) * s2.y, __expf(va.w - s2.x) * s2.y };
        *(float4*)&ta[r][c] = e;
        u16x4 pv = {f2bf(e.x), f2bf(e.y), f2bf(e.z), f2bf(e.w)};
        *(u16x4*)(Pb + (size_t)(i*32 + r) * CTXW2 + j*32 + c) = pv;
    }
    if (i != j) {
        const float2 s2 = st[j*32 + r];
        const float4 vb = *(const float4*)(pji + (size_t)r * TV + c);
        float4 e = { __expf(vb.x - s2.x) * s2.y, __expf(vb.y - s2.x) * s2.y,
                     __expf(vb.z - s2.x) * s2.y, __expf(vb.w - s2.x) * s2.y };
        *(float4*)&tb[r][c] = e;
        u16x4 pv = {f2bf(e.x), f2bf(e.y), f2bf(e.z), f2bf(e.w)};
        *(u16x4*)(Pb + (size_t)(j*32 + r) * CTXW2 + i*32 + c) = pv;
    }
    __syncthreads();
    float4 oa = { ta[c+0][r], ta[c+1][r], ta[c+2][r], ta[c+3][r] };
    *(float4*)(pji + (size_t)r * TV + c) = oa;
    if (i != j) {
        float4 ob = { tb[c+0][r], tb[c+1][r], tb[c+2][r], tb[c+3][r] };
        *(float4*)(pij + (size_t)r * TV + c) = ob;
    }
}

// ------- GEMM3: context = align @ value  (single bf16; NT via Vt) ------------
__global__ __launch_bounds__(256)
void lk_gemm_ctx(const u16* __restrict__ Vt, float* C)
{
    __shared__ u16 lA[128*32], lB[128*32];
    const int b = blockIdx.z;
    const int m0 = blockIdx.x * 128, n0 = blockIdx.y * 128;
    const int t = threadIdx.x;
    const int w = t >> 6, lane = t & 63, l15 = lane & 15, quad = lane >> 4;

    const u16* Pb = (const u16*)C + ((size_t)b * TQ + m0) * CTXW2 + 2*DENC;
    const u16* Bb = Vt + (size_t)b * DENC * TV + (size_t)n0 * TV;

    f32x4 acc[2][8];
    #pragma unroll
    for (int i = 0; i < 2; ++i)
        #pragma unroll
        for (int j = 0; j < 8; ++j) acc[i][j] = (f32x4){0.f,0.f,0.f,0.f};

    for (int k0 = 0; k0 < TV; k0 += 32) {
        stage_tile(lA, Pb + k0, CTXW2, w, lane);
        stage_tile(lB, Bb + k0, TV, w, lane);
        __syncthreads();
        bf16x8 af[2];
        #pragma unroll
        for (int tm = 0; tm < 2; ++tm) {
            const int row = w*32 + tm*16 + l15;
            af[tm] = __builtin_bit_cast(bf16x8, *(const u16x8*)&lA[row*32 + quad*8]);
        }
        #pragma unroll
        for (int tn = 0; tn < 8; ++tn) {
            const int col = tn*16 + l15;
            const bf16x8 bf = __builtin_bit_cast(bf16x8, *(const u16x8*)&lB[col*32 + quad*8]);
            #pragma unroll
            for (int tm = 0; tm < 2; ++tm)
                acc[tm][tn] = __builtin_amdgcn_mfma_f32_16x16x32_bf16(af[tm], bf, acc[tm][tn], 0,0,0);
        }
        __syncthreads();
    }
    float* Cb = C + (size_t)b * TQ * CTXW;
    #pragma unroll
    for (int tm = 0; tm < 2; ++tm)
        #pragma unroll
        for (int tn = 0; tn < 8; ++tn) {
            const int col = n0 + tn*16 + l15;
            #pragma unroll
            for (int r = 0; r < 4; ++r) {
                const int row = m0 + w*32 + tm*16 + quad*4 + r;
                Cb[(size_t)row*CTXW + col] = acc[tm][tn][r];
            }
        }
}

// ---------------- copy query into ctx cols [DENC, DENC+DDEC) -----------------
__global__ __launch_bounds__(256)
void lk_copy_q(const float* __restrict__ Q, float* __restrict__ C)
{
    const size_t idx = (size_t)blockIdx.x * 256 + threadIdx.x;   // float4 index
    const int d4 = (int)(idx & 255);       // DDEC/4 = 256
    const size_t row = idx >> 8;           // b*TQ + q
    const float4 v = *(const float4*)(Q + (row << 10) + 4*d4);
    *(float4*)(C + row * CTXW + DENC + 4*d4) = v;
}

extern "C" void kernel_launch(void* const* d_in, const int* in_sizes, int n_in,
                              void* d_out, int out_size, void* d_ws, size_t ws_size,
                              hipStream_t stream)
{
    (void)in_sizes; (void)n_in; (void)out_size; (void)ws_size;
    const float* Q = (const float*)d_in[0];
    const float* V = (const float*)d_in[1];
    const float* W = (const float*)d_in[2];
    // d_in[3] = bias: softmax-invariant (adds Q·b, constant over v) -> dropped.
    float* out = (float*)d_out;

    float* ctx   = out;                                   // [NB, TQ, CTXW]
    float* align = out + (size_t)NB * TQ * CTXW;          // [NB, TQ, TV]

    // Scores operands staged in the (dead-until-gemm_ctx) ctx region:
    // Q'h/Q'l [NB,TQ,DENC] + Vh/Vl [NB,TV,DENC] = 128 MiB < 192 MiB.
    u16* q2h = (u16*)ctx;
    u16* q2l = q2h + (size_t)NB * TQ * DENC;
    u16* vsh = q2l + (size_t)NB * TQ * DENC;
    u16* vsl = vsh + (size_t)NB * TV * DENC;

    // Qh/Ql bf16 [NB*TQ, DDEC] in the (dead-until-scores) align region.
    u16* qh = (u16*)align;
    u16* ql = qh + (size_t)NB * TQ * DDEC;

    // ws: Wh/Wl (2 MiB) + Vt bf16 [NB,DENC,TV] (32 MiB).
    // sst (softmax partial stats, 4 MiB) aliases Vt: sst lives scores->norm_t,
    // Vt is written only afterwards (prep_vt reads pristine f32 V).
    u16* wh = (u16*)d_ws;
    u16* wl = wh + (size_t)DENC * DDEC;
    u16* vt = wl + (size_t)DENC * DDEC;
    float2* sst = (float2*)vt;

    lk_prep_split<<<DENC*DDEC/1024, 256, 0, stream>>>(W, wh, wl);
    lk_prep_split<<<NB*TQ*DDEC/1024, 256, 0, stream>>>(Q, qh, ql);
    lk_prep_split<<<NB*TV*DENC/1024, 256, 0, stream>>>(V, vsh, vsl);
    lk_gemm_qw<<<dim3(NB*TQ/128, DENC/128), 256, 0, stream>>>(qh, ql, wh, wl, q2h, q2l);
    lk_gemm_scores<<<dim3(TQ/128, TV/128, NB), 256, 0, stream>>>(q2h, q2l, vsh, vsl, align, sst);
    lk_combine<<<NB*TQ/256, 256, 0, stream>>>(sst);
    lk_norm_t<<<dim3(TV/32, TV/32, NB), 256, 0, stream>>>(align, ctx, sst);
    lk_prep_vt<<<dim3(DENC/32, TV/32, NB), 256, 0, stream>>>(V, vt);
    lk_gemm_ctx<<<dim3(TQ/128, DENC/128, NB), 256, 0, stream>>>(vt, ctx);
    lk_copy_q<<<NB*TQ*DDEC/1024, 256, 0, stream>>>(Q, ctx);
}

// Round 3
// 1259.367 us; speedup vs baseline: 1.1888x; 1.0277x over previous
//
#include <hip/hip_runtime.h>
#include <cstdint>
#include <cstddef>

typedef unsigned short u16;
typedef __bf16 bf16x8 __attribute__((ext_vector_type(8)));
typedef unsigned short u16x8 __attribute__((ext_vector_type(8)));
typedef unsigned short u16x4 __attribute__((ext_vector_type(4)));
typedef float f32x4 __attribute__((ext_vector_type(4)));

#define NB   16
#define TQ   2048
#define TV   2048
#define DDEC 1024   // decoder dim (query inner)
#define DENC 512    // encoder dim (value inner / Q' width)
#define CTXW (DENC + DDEC)  // 1536
#define CTXW2 (2*CTXW)      // 3072 : ctx row stride in u16

#define TILE_U16 4096       // one [128][32] u16 tile

// counted-vmcnt pipeline fences (T4): raw barrier, no compiler drain.
#define SBAR()   __builtin_amdgcn_s_barrier()
#define SCHEDB() __builtin_amdgcn_sched_barrier(0)

static __device__ __forceinline__ u16 f2bf(float f) {
    unsigned u = __builtin_bit_cast(unsigned, f);
    return (u16)((u + 0x7fffu + ((u >> 16) & 1u)) >> 16);  // RNE
}
static __device__ __forceinline__ float bf2f(u16 h) {
    return __builtin_bit_cast(float, ((unsigned)h) << 16);
}

// Stage one [128][32]-u16 tile (unpadded, 8 KB) global -> LDS via
// global_load_lds width=16. LDS base per chunk is wave-uniform; HW scatters
// lane i to base + i*16 (m97 structure). 2 VMEM instructions per thread.
static __device__ __forceinline__ void stage_tile(
    u16* __restrict__ lds_tile, const u16* __restrict__ gsrc,
    int ldb, int w, int lane)
{
    #pragma unroll
    for (int p = 0; p < 2; ++p) {
        const int ci  = p * 4 + w;               // chunk 0..7 (1024 B each)
        const int row = ci * 16 + (lane >> 2);
        const int col = (lane & 3) * 8;
        const u16* g = gsrc + (size_t)row * ldb + col;
        u16* l = lds_tile + ci * 512;            // wave-uniform chunk base
        __builtin_amdgcn_global_load_lds(
            (const __attribute__((address_space(1))) void*)g,
            (__attribute__((address_space(3))) void*)l, 16, 0, 0);
    }
}

// -------- elementwise hi/lo split: f32 -> bf16 hi + bf16 lo (same layout) ----
// Used for W [DENC,DDEC], Q [NB*TQ,DDEC], V [NB,TV,DENC].
__global__ __launch_bounds__(256)
void lk_prep_split(const float* __restrict__ X, u16* __restrict__ Xh, u16* __restrict__ Xl)
{
    const size_t i = ((size_t)blockIdx.x * 256 + threadIdx.x) * 4;
    const float4 v = *(const float4*)(X + i);
    const u16 h0=f2bf(v.x), h1=f2bf(v.y), h2=f2bf(v.z), h3=f2bf(v.w);
    u16x4 hv = {h0,h1,h2,h3};
    u16x4 lv = {f2bf(v.x-bf2f(h0)), f2bf(v.y-bf2f(h1)),
                f2bf(v.z-bf2f(h2)), f2bf(v.w-bf2f(h3))};
    *(u16x4*)(Xh + i) = hv;
    *(u16x4*)(Xl + i) = lv;
}

// -------- Vt bf16 [NB,DENC,TV] from pristine f32 V [NB,TV,DENC] --------------
// Runs AFTER norm_t (its ws region aliases the dead softmax-stats buffer).
__global__ __launch_bounds__(256)
void lk_prep_vt(const float* __restrict__ V, u16* __restrict__ Vt)
{
    __shared__ float ts[32][36];
    const int t = threadIdx.x;
    const int r = t >> 3, c = (t & 7) * 4;
    const int e0 = blockIdx.x * 32, v0 = blockIdx.y * 32;
    const float* Vb = V + (size_t)blockIdx.z * TV * DENC;
    const float4 v = *(const float4*)(Vb + (size_t)(v0 + r) * DENC + e0 + c);
    *(float4*)&ts[r][c] = v;
    __syncthreads();
    u16x4 tv = { f2bf(ts[c+0][r]), f2bf(ts[c+1][r]),
                 f2bf(ts[c+2][r]), f2bf(ts[c+3][r]) };
    *(u16x4*)(Vt + (size_t)blockIdx.z * DENC * TV + (size_t)(e0 + r) * TV + v0 + c) = tv;
}

// ------- GEMM1: Q' = Q @ W^T (bf16x3). M=NB*TQ, N=DENC, K=DDEC. -------------
// Counted-vmcnt double-buffered pipeline: tiles t and t+1 in flight.
__global__ __launch_bounds__(256)
void lk_gemm_qw(const u16* __restrict__ Ah_g, const u16* __restrict__ Al_g,
                const u16* __restrict__ Bh_g, const u16* __restrict__ Bl_g,
                u16* __restrict__ Chi, u16* __restrict__ Clo)
{
    __shared__ u16 lAh[2*TILE_U16], lAl[2*TILE_U16], lBh[2*TILE_U16], lBl[2*TILE_U16];
    const int m0 = blockIdx.x * 128, n0 = blockIdx.y * 128;
    const int t = threadIdx.x;
    const int w = t >> 6, lane = t & 63, l15 = lane & 15, quad = lane >> 4;

    const u16* Ab_h = Ah_g + (size_t)m0 * DDEC;
    const u16* Ab_l = Al_g + (size_t)m0 * DDEC;
    const u16* Bb_h = Bh_g + (size_t)n0 * DDEC;
    const u16* Bb_l = Bl_g + (size_t)n0 * DDEC;

    f32x4 acc[2][8];
    #pragma unroll
    for (int i = 0; i < 2; ++i)
        #pragma unroll
        for (int j = 0; j < 8; ++j) acc[i][j] = (f32x4){0.f,0.f,0.f,0.f};

    auto stage4 = [&](int buf, int k0) {
        stage_tile(lAh + buf*TILE_U16, Ab_h + k0, DDEC, w, lane);
        stage_tile(lAl + buf*TILE_U16, Ab_l + k0, DDEC, w, lane);
        stage_tile(lBh + buf*TILE_U16, Bb_h + k0, DDEC, w, lane);
        stage_tile(lBl + buf*TILE_U16, Bb_l + k0, DDEC, w, lane);
    };

    const int nt = DDEC / 32;
    stage4(0, 0);
    stage4(1, 32);
    for (int it = 0; it < nt; ++it) {
        const int cur = it & 1;
        if (it + 1 < nt) { asm volatile("s_waitcnt vmcnt(8)" ::: "memory"); }
        else             { asm volatile("s_waitcnt vmcnt(0)" ::: "memory"); }
        SCHEDB(); SBAR(); SCHEDB();
        const u16* pAh = lAh + cur*TILE_U16;
        const u16* pAl = lAl + cur*TILE_U16;
        const u16* pBh = lBh + cur*TILE_U16;
        const u16* pBl = lBl + cur*TILE_U16;
        bf16x8 ah[2], al[2];
        #pragma unroll
        for (int tm = 0; tm < 2; ++tm) {
            const int row = w*32 + tm*16 + l15;
            ah[tm] = __builtin_bit_cast(bf16x8, *(const u16x8*)&pAh[row*32 + quad*8]);
            al[tm] = __builtin_bit_cast(bf16x8, *(const u16x8*)&pAl[row*32 + quad*8]);
        }
        #pragma unroll
        for (int tn = 0; tn < 8; ++tn) {
            const int col = tn*16 + l15;
            const bf16x8 bh = __builtin_bit_cast(bf16x8, *(const u16x8*)&pBh[col*32 + quad*8]);
            const bf16x8 bl = __builtin_bit_cast(bf16x8, *(const u16x8*)&pBl[col*32 + quad*8]);
            #pragma unroll
            for (int tm = 0; tm < 2; ++tm) {
                acc[tm][tn] = __builtin_amdgcn_mfma_f32_16x16x32_bf16(ah[tm], bh, acc[tm][tn], 0,0,0);
                acc[tm][tn] = __builtin_amdgcn_mfma_f32_16x16x32_bf16(ah[tm], bl, acc[tm][tn], 0,0,0);
                acc[tm][tn] = __builtin_amdgcn_mfma_f32_16x16x32_bf16(al[tm], bh, acc[tm][tn], 0,0,0);
            }
        }
        SBAR();
        if (it + 2 < nt) stage4(cur, (it + 2) * 32);
    }
    #pragma unroll
    for (int tn = 0; tn < 8; ++tn) {
        const int col = n0 + tn*16 + l15;
        #pragma unroll
        for (int tm = 0; tm < 2; ++tm)
            #pragma unroll
            for (int r = 0; r < 4; ++r) {
                const int row = m0 + w*32 + tm*16 + quad*4 + r;
                const float c = acc[tm][tn][r];
                const u16 h = f2bf(c);
                Chi[(size_t)row*DENC + col] = h;
                Clo[(size_t)row*DENC + col] = f2bf(c - bf2f(h));
            }
    }
}

// ------- GEMM2: scores[b,q,v] = Q'[b] @ V[b]^T (bf16x3), K=DENC=512 ----------
// Counted-vmcnt double-buffered pipeline; epilogue emits partial softmax stats.
__global__ __launch_bounds__(256)
void lk_gemm_scores(const u16* __restrict__ Ah_g, const u16* __restrict__ Al_g,
                    const u16* __restrict__ Bh_g, const u16* __restrict__ Bl_g,
                    float* __restrict__ Sc, float2* __restrict__ sst)
{
    __shared__ u16 lAh[2*TILE_U16], lAl[2*TILE_U16], lBh[2*TILE_U16], lBl[2*TILE_U16];
    const int b = blockIdx.z;
    const int m0 = blockIdx.x * 128, n0 = blockIdx.y * 128;
    const int t = threadIdx.x;
    const int w = t >> 6, lane = t & 63, l15 = lane & 15, quad = lane >> 4;

    const u16* Ab_h = Ah_g + (size_t)b * TQ * DENC + (size_t)m0 * DENC;
    const u16* Ab_l = Al_g + (size_t)b * TQ * DENC + (size_t)m0 * DENC;
    const u16* Bb_h = Bh_g + (size_t)b * TV * DENC + (size_t)n0 * DENC;
    const u16* Bb_l = Bl_g + (size_t)b * TV * DENC + (size_t)n0 * DENC;

    f32x4 acc[2][8];
    #pragma unroll
    for (int i = 0; i < 2; ++i)
        #pragma unroll
        for (int j = 0; j < 8; ++j) acc[i][j] = (f32x4){0.f,0.f,0.f,0.f};

    auto stage4 = [&](int buf, int k0) {
        stage_tile(lAh + buf*TILE_U16, Ab_h + k0, DENC, w, lane);
        stage_tile(lAl + buf*TILE_U16, Ab_l + k0, DENC, w, lane);
        stage_tile(lBh + buf*TILE_U16, Bb_h + k0, DENC, w, lane);
        stage_tile(lBl + buf*TILE_U16, Bb_l + k0, DENC, w, lane);
    };

    const int nt = DENC / 32;
    stage4(0, 0);
    stage4(1, 32);
    for (int it = 0; it < nt; ++it) {
        const int cur = it & 1;
        if (it + 1 < nt) { asm volatile("s_waitcnt vmcnt(8)" ::: "memory"); }
        else             { asm volatile("s_waitcnt vmcnt(0)" ::: "memory"); }
        SCHEDB(); SBAR(); SCHEDB();
        const u16* pAh = lAh + cur*TILE_U16;
        const u16* pAl = lAl + cur*TILE_U16;
        const u16* pBh = lBh + cur*TILE_U16;
        const u16* pBl = lBl + cur*TILE_U16;
        bf16x8 ah[2], al[2];
        #pragma unroll
        for (int tm = 0; tm < 2; ++tm) {
            const int row = w*32 + tm*16 + l15;
            ah[tm] = __builtin_bit_cast(bf16x8, *(const u16x8*)&pAh[row*32 + quad*8]);
            al[tm] = __builtin_bit_cast(bf16x8, *(const u16x8*)&pAl[row*32 + quad*8]);
        }
        #pragma unroll
        for (int tn = 0; tn < 8; ++tn) {
            const int col = tn*16 + l15;
            const bf16x8 bh = __builtin_bit_cast(bf16x8, *(const u16x8*)&pBh[col*32 + quad*8]);
            const bf16x8 bl = __builtin_bit_cast(bf16x8, *(const u16x8*)&pBl[col*32 + quad*8]);
            #pragma unroll
            for (int tm = 0; tm < 2; ++tm) {
                acc[tm][tn] = __builtin_amdgcn_mfma_f32_16x16x32_bf16(ah[tm], bh, acc[tm][tn], 0,0,0);
                acc[tm][tn] = __builtin_amdgcn_mfma_f32_16x16x32_bf16(ah[tm], bl, acc[tm][tn], 0,0,0);
                acc[tm][tn] = __builtin_amdgcn_mfma_f32_16x16x32_bf16(al[tm], bh, acc[tm][tn], 0,0,0);
            }
        }
        SBAR();
        if (it + 2 < nt) stage4(cur, (it + 2) * 32);
    }
    float* Sb = Sc + (size_t)b * TQ * TV;
    #pragma unroll
    for (int tm = 0; tm < 2; ++tm)
        #pragma unroll
        for (int tn = 0; tn < 8; ++tn) {
            const int col = n0 + tn*16 + l15;
            #pragma unroll
            for (int r = 0; r < 4; ++r) {
                const int row = m0 + w*32 + tm*16 + quad*4 + r;
                Sb[(size_t)row*TV + col] = acc[tm][tn][r];
            }
        }
    // partial softmax stats for this block's 128 columns.
    const int by = blockIdx.y;
    #pragma unroll
    for (int tm = 0; tm < 2; ++tm)
        #pragma unroll
        for (int r = 0; r < 4; ++r) {
            float m = acc[tm][0][r];
            #pragma unroll
            for (int tn = 1; tn < 8; ++tn) m = fmaxf(m, acc[tm][tn][r]);
            #pragma unroll
            for (int off = 1; off < 16; off <<= 1) m = fmaxf(m, __shfl_xor(m, off, 64));
            float s = 0.f;
            #pragma unroll
            for (int tn = 0; tn < 8; ++tn) s += __expf(acc[tm][tn][r] - m);
            #pragma unroll
            for (int off = 1; off < 16; off <<= 1) s += __shfl_xor(s, off, 64);
            if (l15 == 0) {
                const int row = m0 + w*32 + tm*16 + quad*4 + r;
                sst[((size_t)(b*16 + by))*TQ + row] = (float2){m, s};
            }
        }
}

// ------- combine partial stats -> per-row (max, 1/sum) in the y=0 slot -------
__global__ __launch_bounds__(256)
void lk_combine(float2* __restrict__ sst)
{
    const int rg = blockIdx.x * 256 + threadIdx.x;   // [0, NB*TQ)
    const int b = rg >> 11, q = rg & (TQ - 1);
    float2* base = sst + (size_t)b * 16 * TQ;
    float2 v[16];
    float mx = -3.0e38f;
    #pragma unroll
    for (int y = 0; y < 16; ++y) {
        v[y] = base[(size_t)y * TQ + q];
        mx = fmaxf(mx, v[y].x);
    }
    float s = 0.f;
    #pragma unroll
    for (int y = 0; y < 16; ++y) s += v[y].y * __expf(v[y].x - mx);
    base[q] = (float2){mx, 1.0f / s};   // own slot only -> race-free
}

// ------- fused normalize + in-place transpose + bf16-P emit ------------------
__global__ __launch_bounds__(256)
void lk_norm_t(float* __restrict__ A, float* __restrict__ C,
               const float2* __restrict__ sstF)
{
    const int i = blockIdx.x, j = blockIdx.y;
    if (j < i) return;
    const int b = blockIdx.z;
    float* Ab = A + (size_t)b * TQ * TV;
    u16* Pb = (u16*)C + (size_t)b * TQ * CTXW2 + 2*DENC;
    const float2* st = sstF + (size_t)b * 16 * TQ;   // finals in y=0 slots
    __shared__ float ta[32][36], tb[32][36];
    const int t = threadIdx.x;
    const int r = t >> 3, c = (t & 7) * 4;
    float* pij = Ab + (size_t)(i*32) * TV + j*32;
    float* pji = Ab + (size_t)(j*32) * TV + i*32;
    {
        const float2 s2 = st[i*32 + r];
        const float4 va = *(const float4*)(pij + (size_t)r * TV + c);
        float4 e = { __expf(va.x - s2.x) * s2.y, __expf(va.y - s2.x) * s2.y,
                     __expf(va.z - s2.x) * s2.y, __expf(va.w - s2.x) * s2.y };
        *(float4*)&ta[r][c] = e;
        u16x4 pv = {f2bf(e.x), f2bf(e.y), f2bf(e.z), f2bf(e.w)};
        *(u16x4*)(Pb + (size_t)(i*32 + r) * CTXW2 + j*32 + c) = pv;
    }
    if (i != j) {
        const float2 s2 = st[j*32 + r];
        const float4 vb = *(const float4*)(pji + (size_t)r * TV + c);
        float4 e = { __expf(vb.x - s2.x) * s2.y, __expf(vb.y - s2.x) * s2.y,
                     __expf(vb.z - s2.x) * s2.y, __expf(vb.w - s2.x) * s2.y };
        *(float4*)&tb[r][c] = e;
        u16x4 pv = {f2bf(e.x), f2bf(e.y), f2bf(e.z), f2bf(e.w)};
        *(u16x4*)(Pb + (size_t)(j*32 + r) * CTXW2 + i*32 + c) = pv;
    }
    __syncthreads();
    float4 oa = { ta[c+0][r], ta[c+1][r], ta[c+2][r], ta[c+3][r] };
    *(float4*)(pji + (size_t)r * TV + c) = oa;
    if (i != j) {
        float4 ob = { tb[c+0][r], tb[c+1][r], tb[c+2][r], tb[c+3][r] };
        *(float4*)(pij + (size_t)r * TV + c) = ob;
    }
}

// ------- GEMM3: context = align @ value  (single bf16; NT via Vt) ------------
// Counted-vmcnt double-buffered pipeline (2 tiles -> vmcnt(4)).
__global__ __launch_bounds__(256)
void lk_gemm_ctx(const u16* __restrict__ Vt, float* C)
{
    __shared__ u16 lA[2*TILE_U16], lB[2*TILE_U16];
    const int b = blockIdx.z;
    const int m0 = blockIdx.x * 128, n0 = blockIdx.y * 128;
    const int t = threadIdx.x;
    const int w = t >> 6, lane = t & 63, l15 = lane & 15, quad = lane >> 4;

    const u16* Pb = (const u16*)C + ((size_t)b * TQ + m0) * CTXW2 + 2*DENC;
    const u16* Bb = Vt + (size_t)b * DENC * TV + (size_t)n0 * TV;

    f32x4 acc[2][8];
    #pragma unroll
    for (int i = 0; i < 2; ++i)
        #pragma unroll
        for (int j = 0; j < 8; ++j) acc[i][j] = (f32x4){0.f,0.f,0.f,0.f};

    auto stage2 = [&](int buf, int k0) {
        stage_tile(lA + buf*TILE_U16, Pb + k0, CTXW2, w, lane);
        stage_tile(lB + buf*TILE_U16, Bb + k0, TV, w, lane);
    };

    const int nt = TV / 32;
    stage2(0, 0);
    stage2(1, 32);
    for (int it = 0; it < nt; ++it) {
        const int cur = it & 1;
        if (it + 1 < nt) { asm volatile("s_waitcnt vmcnt(4)" ::: "memory"); }
        else             { asm volatile("s_waitcnt vmcnt(0)" ::: "memory"); }
        SCHEDB(); SBAR(); SCHEDB();
        const u16* pA = lA + cur*TILE_U16;
        const u16* pB = lB + cur*TILE_U16;
        bf16x8 af[2];
        #pragma unroll
        for (int tm = 0; tm < 2; ++tm) {
            const int row = w*32 + tm*16 + l15;
            af[tm] = __builtin_bit_cast(bf16x8, *(const u16x8*)&pA[row*32 + quad*8]);
        }
        #pragma unroll
        for (int tn = 0; tn < 8; ++tn) {
            const int col = tn*16 + l15;
            const bf16x8 bf = __builtin_bit_cast(bf16x8, *(const u16x8*)&pB[col*32 + quad*8]);
            #pragma unroll
            for (int tm = 0; tm < 2; ++tm)
                acc[tm][tn] = __builtin_amdgcn_mfma_f32_16x16x32_bf16(af[tm], bf, acc[tm][tn], 0,0,0);
        }
        SBAR();
        if (it + 2 < nt) stage2(cur, (it + 2) * 32);
    }
    float* Cb = C + (size_t)b * TQ * CTXW;
    #pragma unroll
    for (int tm = 0; tm < 2; ++tm)
        #pragma unroll
        for (int tn = 0; tn < 8; ++tn) {
            const int col = n0 + tn*16 + l15;
            #pragma unroll
            for (int r = 0; r < 4; ++r) {
                const int row = m0 + w*32 + tm*16 + quad*4 + r;
                Cb[(size_t)row*CTXW + col] = acc[tm][tn][r];
            }
        }
}

// ---------------- copy query into ctx cols [DENC, DENC+DDEC) -----------------
__global__ __launch_bounds__(256)
void lk_copy_q(const float* __restrict__ Q, float* __restrict__ C)
{
    const size_t idx = (size_t)blockIdx.x * 256 + threadIdx.x;   // float4 index
    const int d4 = (int)(idx & 255);       // DDEC/4 = 256
    const size_t row = idx >> 8;           // b*TQ + q
    const float4 v = *(const float4*)(Q + (row << 10) + 4*d4);
    *(float4*)(C + row * CTXW + DENC + 4*d4) = v;
}

extern "C" void kernel_launch(void* const* d_in, const int* in_sizes, int n_in,
                              void* d_out, int out_size, void* d_ws, size_t ws_size,
                              hipStream_t stream)
{
    (void)in_sizes; (void)n_in; (void)out_size; (void)ws_size;
    const float* Q = (const float*)d_in[0];
    const float* V = (const float*)d_in[1];
    const float* W = (const float*)d_in[2];
    // d_in[3] = bias: softmax-invariant (adds Q·b, constant over v) -> dropped.
    float* out = (float*)d_out;

    float* ctx   = out;                                   // [NB, TQ, CTXW]
    float* align = out + (size_t)NB * TQ * CTXW;          // [NB, TQ, TV]

    // Scores operands staged in the (dead-until-gemm_ctx) ctx region.
    u16* q2h = (u16*)ctx;
    u16* q2l = q2h + (size_t)NB * TQ * DENC;
    u16* vsh = q2l + (size_t)NB * TQ * DENC;
    u16* vsl = vsh + (size_t)NB * TV * DENC;

    // Qh/Ql bf16 [NB*TQ, DDEC] in the (dead-until-scores) align region.
    u16* qh = (u16*)align;
    u16* ql = qh + (size_t)NB * TQ * DDEC;

    // ws: Wh/Wl (2 MiB) + Vt bf16 [NB,DENC,TV] (32 MiB).
    // sst (4 MiB) aliases Vt: sst lives scores->norm_t, Vt written after.
    u16* wh = (u16*)d_ws;
    u16* wl = wh + (size_t)DENC * DDEC;
    u16* vt = wl + (size_t)DENC * DDEC;
    float2* sst = (float2*)vt;

    lk_prep_split<<<DENC*DDEC/1024, 256, 0, stream>>>(W, wh, wl);
    lk_prep_split<<<NB*TQ*DDEC/1024, 256, 0, stream>>>(Q, qh, ql);
    lk_prep_split<<<NB*TV*DENC/1024, 256, 0, stream>>>(V, vsh, vsl);
    lk_gemm_qw<<<dim3(NB*TQ/128, DENC/128), 256, 0, stream>>>(qh, ql, wh, wl, q2h, q2l);
    lk_gemm_scores<<<dim3(TQ/128, TV/128, NB), 256, 0, stream>>>(q2h, q2l, vsh, vsl, align, sst);
    lk_combine<<<NB*TQ/256, 256, 0, stream>>>(sst);
    lk_norm_t<<<dim3(TV/32, TV/32, NB), 256, 0, stream>>>(align, ctx, sst);
    lk_prep_vt<<<dim3(DENC/32, TV/32, NB), 256, 0, stream>>>(V, vt);
    lk_gemm_ctx<<<dim3(TQ/128, DENC/128, NB), 256, 0, stream>>>(vt, ctx);
    lk_copy_q<<<NB*TQ*DDEC/1024, 256, 0, stream>>>(Q, ctx);
}